// Round 1
// baseline (66.899 us; speedup 1.0000x reference)
//
#include <hip/hip_runtime.h>
#include <math.h>

// Problem constants (from reference): B=64, F=2048, D=64.
#define FNUM 2048
#define DDIM 64
#define BATCH 64

// Key identity: sum_{f,g} (e_f . e_g) = || sum_f e_f ||^2 with e_f = x_f * V_f.
// So pred[b] = sigmoid(gb + sum_f x[b,f]*bias[f] + sum_d (sum_f x[b,f]*V[f,d])^2).
// One block per batch row. 256 threads: thread t -> fbase = t>>4 (f-lane 0..15),
// dg = t&15 (float4 d-group). Wave reads 4 consecutive embed rows per iter
// (64 lanes x 16B = 1KB coalesced).
__global__ __launch_bounds__(256)
void KTM_22110491640579_kernel(const float* __restrict__ data,   // B x F
                               const float* __restrict__ embed,  // F x D
                               const float* __restrict__ bias,   // F
                               const float* __restrict__ gbias,  // 1
                               float* __restrict__ out)          // B
{
    const int b = blockIdx.x;
    const int t = threadIdx.x;

    __shared__ float xs[FNUM];        // 8 KB: data row
    __shared__ float red[16][DDIM];   // 4 KB: per-fbase partial S_d
    __shared__ float lin_red[256];    // 1 KB: linear-term partials

    // Stage data row b into LDS with float4 loads (2 iters x 256 thr x 16B).
    {
        const float4* drow = (const float4*)(data + (size_t)b * FNUM);
        float4* xs4 = (float4*)xs;
        xs4[t]       = drow[t];
        xs4[t + 256] = drow[t + 256];
    }
    __syncthreads();

    // Main accumulation: S[d] = sum_f x[f] * V[f][d], split 16-way over f.
    const int fbase = t >> 4;   // 0..15
    const int dg    = t & 15;   // 0..15 (covers d = 4*dg .. 4*dg+3)
    const float4* E4 = (const float4*)embed;  // FNUM rows x 16 float4
    float4 acc = make_float4(0.f, 0.f, 0.f, 0.f);
    #pragma unroll 8
    for (int i = 0; i < FNUM / 16; ++i) {     // 128 iterations
        const int f = i * 16 + fbase;
        const float x = xs[f];
        const float4 e = E4[f * 16 + dg];
        acc.x += x * e.x;
        acc.y += x * e.y;
        acc.z += x * e.z;
        acc.w += x * e.w;
    }
    red[fbase][dg * 4 + 0] = acc.x;
    red[fbase][dg * 4 + 1] = acc.y;
    red[fbase][dg * 4 + 2] = acc.z;
    red[fbase][dg * 4 + 3] = acc.w;

    // Linear term partials: lin = sum_f x[f] * bias[f].
    float lacc = 0.f;
    #pragma unroll
    for (int i = 0; i < FNUM / 256; ++i) {    // 8 iterations
        const int f = t + i * 256;
        lacc += xs[f] * bias[f];
    }
    lin_red[t] = lacc;
    __syncthreads();

    // Final reduce in wave 0: S_d, square, add lin partials, shuffle-sum.
    if (t < 64) {
        float s = 0.f;
        #pragma unroll
        for (int fb = 0; fb < 16; ++fb) s += red[fb][t];
        float val = s * s;
        val += lin_red[t] + lin_red[t + 64] + lin_red[t + 128] + lin_red[t + 192];
        #pragma unroll
        for (int off = 32; off > 0; off >>= 1)
            val += __shfl_down(val, off, 64);
        if (t == 0) {
            const float z = gbias[0] + val;
            out[b] = 1.0f / (1.0f + expf(-z));
        }
    }
}

extern "C" void kernel_launch(void* const* d_in, const int* in_sizes, int n_in,
                              void* d_out, int out_size, void* d_ws, size_t ws_size,
                              hipStream_t stream) {
    const float* data  = (const float*)d_in[0];  // (64, 2048)
    const float* embed = (const float*)d_in[1];  // (2048, 64)
    const float* bias  = (const float*)d_in[2];  // (2048, 1)
    const float* gb    = (const float*)d_in[3];  // (1, 1)
    float* out = (float*)d_out;                  // (64,)

    KTM_22110491640579_kernel<<<BATCH, 256, 0, stream>>>(data, embed, bias, gb, out);
}

// Round 2
// 65.436 us; speedup vs baseline: 1.0224x; 1.0224x over previous
//
#include <hip/hip_runtime.h>
#include <math.h>

// Problem constants (from reference): B=64, F=2048, D=64.
#define FNUM 2048
#define DDIM 64
#define BATCH 64

// Identity: sum_{f,g} (e_f . e_g) = ||sum_f e_f||^2 with e_f = x_f * V_f.
// pred[b] = sigmoid(gb + sum_f x[b,f]*bias[f] + sum_d (sum_f x[b,f]*V[f,d])^2).
//
// v2: one block per batch row, 1024 threads (16 waves -> 4 waves/SIMD for
// latency hiding; v1 had 1 wave/SIMD). Thread t: fbase = t>>4 (f-lane 0..63),
// dg = t&15 (float4 d-group). 32 main-loop iterations per thread.
__global__ __launch_bounds__(1024)
void KTM_22110491640579_kernel(const float* __restrict__ data,   // B x F
                               const float* __restrict__ embed,  // F x D
                               const float* __restrict__ bias,   // F
                               const float* __restrict__ gbias,  // 1
                               float* __restrict__ out)          // B
{
    const int b = blockIdx.x;
    const int t = threadIdx.x;

    __shared__ float  xs[FNUM];        // 8 KB: data row
    __shared__ float4 red4[64][16];    // 16 KB: per-fbase partial S (64 floats/row)
    __shared__ float  lin_red[16];     // per-wave linear-term partials

    // Stage data row b into LDS: 512 float4 loads by first 512 threads.
    if (t < 512) {
        ((float4*)xs)[t] = ((const float4*)(data + (size_t)b * FNUM))[t];
    }
    __syncthreads();

    // S[d] = sum_f x[f] * V[f][d], f split 64-way across fbase.
    const int fbase = t >> 4;   // 0..63
    const int dg    = t & 15;   // 0..15 (d = 4*dg .. 4*dg+3)
    const float4* E4 = (const float4*)embed;  // FNUM rows x 16 float4
    float4 acc = make_float4(0.f, 0.f, 0.f, 0.f);
    #pragma unroll 8
    for (int i = 0; i < FNUM / 64; ++i) {     // 32 iterations
        const int f = i * 64 + fbase;
        const float x = xs[f];                // broadcast within 16-lane group
        const float4 e = E4[f * 16 + dg];
        acc.x += x * e.x;
        acc.y += x * e.y;
        acc.z += x * e.z;
        acc.w += x * e.w;
    }
    red4[fbase][dg] = acc;

    // Linear term: lin = sum_f x[f]*bias[f]; 2 elems/thread, wave-shuffle reduce.
    {
        float lacc = xs[t] * bias[t] + xs[t + 1024] * bias[t + 1024];
        #pragma unroll
        for (int off = 32; off > 0; off >>= 1)
            lacc += __shfl_down(lacc, off, 64);
        if ((t & 63) == 0) lin_red[t >> 6] = lacc;
    }
    __syncthreads();

    // Final reduce in wave 0: S_d = sum over 64 fbase rows, square, + lin, sigmoid.
    if (t < 64) {
        float s = 0.f;
        #pragma unroll
        for (int fb = 0; fb < 64; ++fb) {
            const float* row = (const float*)&red4[fb][0];  // 64 floats
            s += row[t];
        }
        float val = s * s;
        if (t < 16) val += lin_red[t];
        #pragma unroll
        for (int off = 32; off > 0; off >>= 1)
            val += __shfl_down(val, off, 64);
        if (t == 0) {
            const float z = gbias[0] + val;
            out[b] = 1.0f / (1.0f + expf(-z));
        }
    }
}

extern "C" void kernel_launch(void* const* d_in, const int* in_sizes, int n_in,
                              void* d_out, int out_size, void* d_ws, size_t ws_size,
                              hipStream_t stream) {
    const float* data  = (const float*)d_in[0];  // (64, 2048)
    const float* embed = (const float*)d_in[1];  // (2048, 64)
    const float* bias  = (const float*)d_in[2];  // (2048, 1)
    const float* gb    = (const float*)d_in[3];  // (1, 1)
    float* out = (float*)d_out;                  // (64,)

    KTM_22110491640579_kernel<<<BATCH, 1024, 0, stream>>>(data, embed, bias, gb, out);
}